// Round 15
// baseline (126.854 us; speedup 1.0000x reference)
//
#include <hip/hip_runtime.h>
#include <math.h>

#define BB 1024   // batch
#define VV 256    // variables
#define KK 64     // categories
#define N0 8192   // input nodes
#define CC 32     // sum-node children

#define LOG2E 1.4426950408889634f
#define LN2   0.6931471805599453f
// layer-1 weight scale 2^13 centers linear-domain values near 2^0;
// accumulated scale at the root su is 2^(8*13) = 2^104.
#define W1SCALE 8192.0f
#define ROOT_LOG2_SCALE 104.0f

static __device__ __forceinline__ float flog2(float x) { return __builtin_amdgcn_logf(x); }
static __device__ __forceinline__ float asf(unsigned int u) {
    union { unsigned int i; float f; } c; c.i = u; return c.f;
}
static __device__ __forceinline__ unsigned int asu(float f) {
    union { float f; unsigned int i; } c; c.f = f; return c.i;
}
static __device__ __forceinline__ float bf2f(unsigned short u) {
    return asf((unsigned int)u << 16);
}
static __device__ __forceinline__ unsigned short f2bf(float f) {
    unsigned int i = asu(f);
    unsigned int r = i + 0x7FFFu + ((i >> 16) & 1u);  // RNE
    return (unsigned short)(r >> 16);
}

// ---------------------------------------------------------------------------
// prep (linear domain, BYTE-OFFSET indices: all local ids *8, fits u16):
//  bid <  2048 : lpT[k][i] = softmax(in_logits[i])[k]      (bf16, TRANSPOSED)
//  bid <  2944 : spk[n][c] = (cid*8) | (bf16 lin-weight <<16); layer1 w *= 2^13
//  bid <  3000 : ppk[e]    = (p0*8) | ((p1*8) << 16)
//  bid == 3000 : rpk[c]    = {p0*8, p1*8, bf16 softmax(w4), 0}
// ---------------------------------------------------------------------------
__global__ void __launch_bounds__(256) k_prep(
        const float* __restrict__ logits,
        const float* __restrict__ w1, const float* __restrict__ w2,
        const float* __restrict__ w3, const float* __restrict__ w4,
        const int* __restrict__ cids1, const int* __restrict__ cids2,
        const int* __restrict__ cids3, const int* __restrict__ cids4,
        const int* __restrict__ pids1, const int* __restrict__ pids2,
        const int* __restrict__ pids3, const int* __restrict__ pids4,
        unsigned short* __restrict__ lpT, unsigned int* __restrict__ ppk,
        unsigned int* __restrict__ spk, ushort4* __restrict__ rpk) {
    int bid = blockIdx.x, tid = threadIdx.x;
    __shared__ unsigned short tile[4][64];
    if (bid < 2048) {
        int i = bid * 4 + (tid >> 6);
        int k = tid & 63;
        float l = logits[(size_t)i * KK + k];
        float m = l;
        #pragma unroll
        for (int d = 32; d; d >>= 1) m = fmaxf(m, __shfl_xor(m, d));
        float e = __expf(l - m);
        float s = e;
        #pragma unroll
        for (int d = 32; d; d >>= 1) s += __shfl_xor(s, d);
        tile[tid >> 6][k] = f2bf(e / s);          // linear softmax prob
        __syncthreads();
        if (tid < 64) {  // transposed store: 4 consecutive i per k
            ushort4 o;
            o.x = tile[0][tid]; o.y = tile[1][tid];
            o.z = tile[2][tid]; o.w = tile[3][tid];
            *(ushort4*)(lpT + (size_t)tid * N0 + bid * 4) = o;
        }
    } else if (bid < 2944) {
        int n = (bid - 2048) * 8 + (tid >> 5);
        int lane = tid & 31;
        if (n < 7168) {
            const float* wsrc; const int* csrc; float scale;
            if (n < 4096)      { wsrc = w1 + (size_t)n * CC;          csrc = cids1 + (size_t)n * CC;          scale = W1SCALE; }
            else if (n < 6144) { wsrc = w2 + (size_t)(n - 4096) * CC; csrc = cids2 + (size_t)(n - 4096) * CC; scale = 1.0f; }
            else               { wsrc = w3 + (size_t)(n - 6144) * CC; csrc = cids3 + (size_t)(n - 6144) * CC; scale = 1.0f; }
            float lw = wsrc[lane];
            float m = lw;
            #pragma unroll
            for (int d = 16; d; d >>= 1) m = fmaxf(m, __shfl_xor(m, d, 32));
            float e = __expf(lw - m);
            float s = e;
            #pragma unroll
            for (int d = 16; d; d >>= 1) s += __shfl_xor(s, d, 32);
            unsigned int cid8 = (unsigned int)(csrc[lane] - 1) * 8u;
            spk[(size_t)n * CC + lane] = cid8 | ((unsigned int)f2bf(e / s * scale) << 16);
        }
    } else if (bid < 3000) {
        int idx = (bid - 2944) * 256 + tid;  // 14336 elements total
        int p0, p1;
        if (idx < 8192)       { p0 = pids1[idx * 2] - 1;                p1 = pids1[idx * 2 + 1] - 1; }
        else if (idx < 12288) { int e = idx - 8192;  p0 = pids2[e * 2] - 8193;  p1 = pids2[e * 2 + 1] - 8193; }
        else                  { int e = idx - 12288; p0 = pids3[e * 2] - 12289; p1 = pids3[e * 2 + 1] - 12289; }
        ppk[idx] = ((unsigned int)p0 * 8u) | (((unsigned int)p1 * 8u) << 16);
    } else {
        if (tid < CC) {
            float lw = w4[tid];
            float m = lw;
            #pragma unroll
            for (int d = 16; d; d >>= 1) m = fmaxf(m, __shfl_xor(m, d, 32));
            float e = __expf(lw - m);
            float s = e;
            #pragma unroll
            for (int d = 16; d; d >>= 1) s += __shfl_xor(s, d, 32);
            int el = cids4[tid] - 1;
            ushort4 r;
            r.x = (unsigned short)((pids4[el * 2]     - 14337) * 8);
            r.y = (unsigned short)((pids4[el * 2 + 1] - 14337) * 8);
            r.z = f2bf(e / s); r.w = 0;
            rpk[tid] = r;
        }
    }
}

// ---------------------------------------------------------------------------
// One layer for a 4-column slice, linear domain. Compile-time E/S: fully
// unrolled, zero bounds logic. bf16 unpack via bit tricks on uint2 views:
// hi bf16 of a u32 IS an f32 after masking (1 v_and); lo needs 1 v_lshl.
// Packed weight in metadata hi16 -> f32 with a single v_and.
// ---------------------------------------------------------------------------
template <int E, int S, typename NMP>
static __device__ __forceinline__ void do_layer(
        NMP nm4, ushort4* em4,
        const unsigned int* __restrict__ pp, const unsigned int* __restrict__ sp,
        int tid) {
    const char* nmB = (const char*)&nm4[0];
    const char* emB = (const char*)&em4[0];
    // ---- prod: E/1024 elements per thread, batches of <=4, exact fit.
    {
        constexpr int PT = E / 1024;              // 8, 4, 2
        constexpr int BAT = (PT >= 4) ? 4 : PT;   // 4, 4, 2
        constexpr int IT = PT / BAT;              // 2, 1, 1
        #pragma unroll
        for (int r = 0; r < IT; ++r) {
            int e0 = tid + r * 1024 * BAT;
            unsigned int pw[BAT];
            uint2 av[BAT], bv[BAT];
            #pragma unroll
            for (int j = 0; j < BAT; ++j) pw[j] = pp[e0 + j * 1024];
            #pragma unroll
            for (int j = 0; j < BAT; ++j) {
                av[j] = *(const uint2*)(nmB + (pw[j] & 0xFFFFu));
                bv[j] = *(const uint2*)(nmB + (pw[j] >> 16));
            }
            #pragma unroll
            for (int j = 0; j < BAT; ++j) {
                float p0 = asf(av[j].x << 16)        * asf(bv[j].x << 16);
                float p1 = asf(av[j].x & 0xFFFF0000u) * asf(bv[j].x & 0xFFFF0000u);
                float p2 = asf(av[j].y << 16)        * asf(bv[j].y << 16);
                float p3 = asf(av[j].y & 0xFFFF0000u) * asf(bv[j].y & 0xFFFF0000u);
                uint2 o;
                o.x = ((unsigned int)f2bf(p1) << 16) | f2bf(p0);
                o.y = ((unsigned int)f2bf(p3) << 16) | f2bf(p2);
                *(uint2*)(emB + (size_t)(e0 + j * 1024) * 8) = o;
            }
        }
    }
    __syncthreads();
    // ---- sum: S/1024 nodes per thread, 2 groups of 16 gathers each.
    {
        constexpr int ST = S / 1024;              // 4, 2, 1
        #pragma unroll
        for (int r = 0; r < ST; ++r) {
            int s = tid + r * 1024;
            const uint4* base = (const uint4*)(sp + (size_t)s * CC);
            uint4 q[8];
            #pragma unroll
            for (int j = 0; j < 8; ++j) q[j] = base[j];
            unsigned int uu[32];
            #pragma unroll
            for (int j = 0; j < 8; ++j) {
                uu[j * 4 + 0] = q[j].x; uu[j * 4 + 1] = q[j].y;
                uu[j * 4 + 2] = q[j].z; uu[j * 4 + 3] = q[j].w;
            }
            float sux = 0.f, suy = 0.f, suz = 0.f, suw = 0.f;
            #pragma unroll
            for (int h = 0; h < 2; ++h) {
                uint2 t[16];
                #pragma unroll
                for (int c = 0; c < 16; ++c)
                    t[c] = *(const uint2*)(emB + (uu[h * 16 + c] & 0xFFFFu));
                #pragma unroll
                for (int c = 0; c < 16; ++c) {
                    float w = asf(uu[h * 16 + c] & 0xFFFF0000u);  // hi16 bf16 == f32
                    sux = fmaf(asf(t[c].x << 16),         w, sux);
                    suy = fmaf(asf(t[c].x & 0xFFFF0000u), w, suy);
                    suz = fmaf(asf(t[c].y << 16),         w, suz);
                    suw = fmaf(asf(t[c].y & 0xFFFF0000u), w, suw);
                }
            }
            ushort4 o;
            o.x = f2bf(sux); o.y = f2bf(suy);
            o.z = f2bf(suz); o.w = f2bf(suw);
            nm4[s] = o;
        }
    }
    __syncthreads();
}

template <typename NMP>
static __device__ __forceinline__ void do_root(NMP nm4, const ushort4* __restrict__ rpk,
                                               float* __restrict__ out, int b0, int tid) {
    const char* nmB = (const char*)&nm4[0];
    if (tid < 4) {
        int col = tid;
        float su = 0.f;
        #pragma unroll
        for (int c = 0; c < CC; ++c) {
            ushort4 r = rpk[c];
            ushort4 a = *(const ushort4*)(nmB + r.x);
            ushort4 b = *(const ushort4*)(nmB + r.y);
            const unsigned short* ap = &a.x;
            const unsigned short* bp = &b.x;
            su = fmaf(bf2f(ap[col]) * bf2f(bp[col]), bf2f(r.z), su);
        }
        out[b0 + col] = (flog2(su) - ROOT_LOG2_SCALE) * LN2;
    }
}

// ---------------------------------------------------------------------------
// mega A: block owns 4 batch cols; nm AND em slices in LDS (135 KB, dynamic
// opt-in). 1024 threads. Whole net, __syncthreads-only between phases.
// ---------------------------------------------------------------------------
__global__ void __launch_bounds__(1024, 1) k_mega_lds(
        const int* __restrict__ x, const unsigned short* __restrict__ lpT,
        const unsigned int* __restrict__ ppk, const unsigned int* __restrict__ spk,
        const ushort4* __restrict__ rpk, float* __restrict__ out) {
    extern __shared__ ushort4 smem4[];
    ushort4* nm4 = smem4;                 // [8192] = 64 KB
    ushort4* em4 = smem4 + 8192;          // [8192] = 64 KB
    int* xv = (int*)(smem4 + 16384);      // [4][256] = 4 KB
    int tid = threadIdx.x;
    int b0 = blockIdx.x * 4;

    {
        int c = tid >> 8, v = tid & 255;
        xv[tid] = x[(b0 + c) * VV + v];
    }
    __syncthreads();
    for (int i = tid; i < N0; i += 1024) {   // input gather via transposed lpT
        int v = i >> 5;
        ushort4 o;
        o.x = lpT[(size_t)xv[v]       * N0 + i];
        o.y = lpT[(size_t)xv[256 + v] * N0 + i];
        o.z = lpT[(size_t)xv[512 + v] * N0 + i];
        o.w = lpT[(size_t)xv[768 + v] * N0 + i];
        nm4[i] = o;
    }
    __syncthreads();
    do_layer<8192, 4096>(nm4, em4, ppk,         spk,          tid);
    do_layer<4096, 2048>(nm4, em4, ppk + 8192,  spk + 131072, tid);
    do_layer<2048, 1024>(nm4, em4, ppk + 12288, spk + 196608, tid);
    do_root(nm4, rpk, out, b0, tid);
}

// ---------------------------------------------------------------------------
// mega B (fallback if >64KB LDS opt-in fails): em in LDS (64 KB), nm in a
// per-block global slice.
// ---------------------------------------------------------------------------
__global__ void __launch_bounds__(1024, 1) k_mega_glb(
        const int* __restrict__ x, const unsigned short* __restrict__ lpT,
        const unsigned int* __restrict__ ppk, const unsigned int* __restrict__ spk,
        const ushort4* __restrict__ rpk, ushort4* __restrict__ nmg,
        float* __restrict__ out) {
    extern __shared__ ushort4 smem4[];
    ushort4* em4 = smem4;                              // [8192] = 64 KB
    ushort4* nm4 = nmg + (size_t)blockIdx.x * 8192;    // global slice
    int tid = threadIdx.x;
    int b0 = blockIdx.x * 4;

    for (int i = tid; i < N0; i += 1024) {
        int v = i >> 5;
        int x0 = x[(b0 + 0) * VV + v], x1 = x[(b0 + 1) * VV + v];
        int x2 = x[(b0 + 2) * VV + v], x3 = x[(b0 + 3) * VV + v];
        ushort4 o;
        o.x = lpT[(size_t)x0 * N0 + i];
        o.y = lpT[(size_t)x1 * N0 + i];
        o.z = lpT[(size_t)x2 * N0 + i];
        o.w = lpT[(size_t)x3 * N0 + i];
        nm4[i] = o;
    }
    __syncthreads();
    do_layer<8192, 4096>(nm4, em4, ppk,         spk,          tid);
    do_layer<4096, 2048>(nm4, em4, ppk + 8192,  spk + 131072, tid);
    do_layer<2048, 1024>(nm4, em4, ppk + 12288, spk + 196608, tid);
    do_root(nm4, rpk, out, b0, tid);
}

// ---------------------------------------------------------------------------
// Launch: 2 dispatches (prep + mega). Deterministic A/B pick by whether the
// 135 KB dynamic-LDS opt-in succeeds.
// ---------------------------------------------------------------------------
extern "C" void kernel_launch(void* const* d_in, const int* in_sizes, int n_in,
                              void* d_out, int out_size, void* d_ws, size_t ws_size,
                              hipStream_t stream) {
    const int*   x         = (const int*)  d_in[0];
    const float* in_logits = (const float*)d_in[1];
    const float* w1        = (const float*)d_in[2];
    const float* w2        = (const float*)d_in[3];
    const float* w3        = (const float*)d_in[4];
    const float* w4        = (const float*)d_in[5];
    const int*   pids1     = (const int*)  d_in[6];
    const int*   pids2     = (const int*)  d_in[7];
    const int*   pids3     = (const int*)  d_in[8];
    const int*   pids4     = (const int*)  d_in[9];
    const int*   cids1     = (const int*)  d_in[10];
    const int*   cids2     = (const int*)  d_in[11];
    const int*   cids3     = (const int*)  d_in[12];
    const int*   cids4     = (const int*)  d_in[13];
    float* out = (float*)d_out;

    char* ws = (char*)d_ws;
    unsigned short* lpT = (unsigned short*)ws;                    // 64*8192 bf16 = 1 MB
    unsigned int*   ppk = (unsigned int*)(ws + 1048576);          // 14336 u32
    unsigned int*   spk = (unsigned int*)(ws + 1105920);          // 229376 u32
    ushort4*        rpk = (ushort4*)(ws + 2023424);               // 32 x 8 B
    ushort4*        nmg = (ushort4*)(ws + 2023936);               // 256*8192*8 B = 16 MB (B only)

    k_prep<<<3001, 256, 0, stream>>>(in_logits, w1, w2, w3, w4,
                                     cids1, cids2, cids3, cids4,
                                     pids1, pids2, pids3, pids4,
                                     lpT, ppk, spk, rpk);

    const int SMEM_A = 135168;  // 64K nm + 64K em + 4K xv
    const int SMEM_B = 65536;   // 64K em
    hipError_t e = hipFuncSetAttribute((const void*)k_mega_lds,
                                       hipFuncAttributeMaxDynamicSharedMemorySize, SMEM_A);
    if (e == hipSuccess) {
        k_mega_lds<<<256, 1024, SMEM_A, stream>>>(x, lpT, ppk, spk, rpk, out);
    } else {
        (void)hipGetLastError();  // clear sticky error from failed opt-in
        hipFuncSetAttribute((const void*)k_mega_glb,
                            hipFuncAttributeMaxDynamicSharedMemorySize, SMEM_B);
        k_mega_glb<<<256, 1024, SMEM_B, stream>>>(x, lpT, ppk, spk, rpk, nmg, out);
    }
}

// Round 16
// 124.460 us; speedup vs baseline: 1.0192x; 1.0192x over previous
//
#include <hip/hip_runtime.h>
#include <math.h>

#define BB 1024   // batch
#define VV 256    // variables
#define KK 64     // categories
#define N0 8192   // input nodes
#define CC 32     // sum-node children

#define LOG2E 1.4426950408889634f
#define LN2   0.6931471805599453f
// layer-1 weight scale 2^13 centers linear-domain values near 2^0;
// accumulated scale at the root su is 2^(8*13) = 2^104.
#define W1SCALE 8192.0f
#define ROOT_LOG2_SCALE 104.0f

static __device__ __forceinline__ float flog2(float x) { return __builtin_amdgcn_logf(x); }
static __device__ __forceinline__ float bf2f(unsigned short u) {
    union { unsigned int i; float f; } c; c.i = (unsigned int)u << 16; return c.f;
}
static __device__ __forceinline__ unsigned short f2bf(float f) {
    union { float f; unsigned int i; } c; c.f = f;
    unsigned int r = c.i + 0x7FFFu + ((c.i >> 16) & 1u);  // RNE
    return (unsigned short)(r >> 16);
}

// ---------------------------------------------------------------------------
// prep (linear domain, BYTE-OFFSET indices: all local ids *8, fits u16):
//  bid <  2048 : lpT[k][i] = softmax(in_logits[i])[k]      (bf16, TRANSPOSED)
//  bid <  2944 : spk[n][c] = (cid*8) | (bf16 lin-weight <<16); layer1 w *= 2^13
//  bid <  3000 : ppk[e]    = (p0*8) | ((p1*8) << 16)
//  bid == 3000 : rpk[c]    = {p0*8, p1*8, bf16 softmax(w4), 0}
// ---------------------------------------------------------------------------
__global__ void __launch_bounds__(256) k_prep(
        const float* __restrict__ logits,
        const float* __restrict__ w1, const float* __restrict__ w2,
        const float* __restrict__ w3, const float* __restrict__ w4,
        const int* __restrict__ cids1, const int* __restrict__ cids2,
        const int* __restrict__ cids3, const int* __restrict__ cids4,
        const int* __restrict__ pids1, const int* __restrict__ pids2,
        const int* __restrict__ pids3, const int* __restrict__ pids4,
        unsigned short* __restrict__ lpT, unsigned int* __restrict__ ppk,
        unsigned int* __restrict__ spk, ushort4* __restrict__ rpk) {
    int bid = blockIdx.x, tid = threadIdx.x;
    __shared__ unsigned short tile[4][64];
    if (bid < 2048) {
        int i = bid * 4 + (tid >> 6);
        int k = tid & 63;
        float l = logits[(size_t)i * KK + k];
        float m = l;
        #pragma unroll
        for (int d = 32; d; d >>= 1) m = fmaxf(m, __shfl_xor(m, d));
        float e = __expf(l - m);
        float s = e;
        #pragma unroll
        for (int d = 32; d; d >>= 1) s += __shfl_xor(s, d);
        tile[tid >> 6][k] = f2bf(e / s);          // linear softmax prob
        __syncthreads();
        if (tid < 64) {  // transposed store: 4 consecutive i per k
            ushort4 o;
            o.x = tile[0][tid]; o.y = tile[1][tid];
            o.z = tile[2][tid]; o.w = tile[3][tid];
            *(ushort4*)(lpT + (size_t)tid * N0 + bid * 4) = o;
        }
    } else if (bid < 2944) {
        int n = (bid - 2048) * 8 + (tid >> 5);
        int lane = tid & 31;
        if (n < 7168) {
            const float* wsrc; const int* csrc; float scale;
            if (n < 4096)      { wsrc = w1 + (size_t)n * CC;          csrc = cids1 + (size_t)n * CC;          scale = W1SCALE; }
            else if (n < 6144) { wsrc = w2 + (size_t)(n - 4096) * CC; csrc = cids2 + (size_t)(n - 4096) * CC; scale = 1.0f; }
            else               { wsrc = w3 + (size_t)(n - 6144) * CC; csrc = cids3 + (size_t)(n - 6144) * CC; scale = 1.0f; }
            float lw = wsrc[lane];
            float m = lw;
            #pragma unroll
            for (int d = 16; d; d >>= 1) m = fmaxf(m, __shfl_xor(m, d, 32));
            float e = __expf(lw - m);
            float s = e;
            #pragma unroll
            for (int d = 16; d; d >>= 1) s += __shfl_xor(s, d, 32);
            unsigned int cid8 = (unsigned int)(csrc[lane] - 1) * 8u;
            spk[(size_t)n * CC + lane] = cid8 | ((unsigned int)f2bf(e / s * scale) << 16);
        }
    } else if (bid < 3000) {
        int idx = (bid - 2944) * 256 + tid;  // 14336 elements total
        int p0, p1;
        if (idx < 8192)       { p0 = pids1[idx * 2] - 1;                p1 = pids1[idx * 2 + 1] - 1; }
        else if (idx < 12288) { int e = idx - 8192;  p0 = pids2[e * 2] - 8193;  p1 = pids2[e * 2 + 1] - 8193; }
        else                  { int e = idx - 12288; p0 = pids3[e * 2] - 12289; p1 = pids3[e * 2 + 1] - 12289; }
        ppk[idx] = ((unsigned int)p0 * 8u) | (((unsigned int)p1 * 8u) << 16);
    } else {
        if (tid < CC) {
            float lw = w4[tid];
            float m = lw;
            #pragma unroll
            for (int d = 16; d; d >>= 1) m = fmaxf(m, __shfl_xor(m, d, 32));
            float e = __expf(lw - m);
            float s = e;
            #pragma unroll
            for (int d = 16; d; d >>= 1) s += __shfl_xor(s, d, 32);
            int el = cids4[tid] - 1;
            ushort4 r;
            r.x = (unsigned short)((pids4[el * 2]     - 14337) * 8);
            r.y = (unsigned short)((pids4[el * 2 + 1] - 14337) * 8);
            r.z = f2bf(e / s); r.w = 0;
            rpk[tid] = r;
        }
    }
}

// ---------------------------------------------------------------------------
// One layer for a 4-column slice, linear domain, load-batched (R14 best).
// prod: em[e] = nm[p0]*nm[p1], 4 elements batched (8 loads in flight).
// sum: per node, 32 ds_read_b64 requested back-to-back (compiler grants ~6
// in flight at VGPR 48 — empirically the best schedule it will produce),
// then 128 FMAs. Indices are byte offsets (pre-scaled *8 in prep).
// ---------------------------------------------------------------------------
template <typename NMP>
static __device__ __forceinline__ void do_layer(
        NMP nm4, ushort4* em4,
        const unsigned int* __restrict__ pp, const unsigned int* __restrict__ sp,
        int E, int S, int tid, int nthr) {
    const char* nmB = (const char*)&nm4[0];
    const char* emB = (const char*)&em4[0];
    for (int e = tid; e < E; e += nthr * 4) {
        unsigned int pw[4];
        ushort4 av[4], bv[4];
        int cnt = 0;
        #pragma unroll
        for (int j = 0; j < 4; ++j) {
            int ee = e + j * nthr;
            if (ee < E) { pw[j] = pp[ee]; ++cnt; }
        }
        #pragma unroll
        for (int j = 0; j < 4; ++j) {
            if (j < cnt) {
                av[j] = *(const ushort4*)(nmB + (pw[j] & 0xFFFFu));
                bv[j] = *(const ushort4*)(nmB + (pw[j] >> 16));
            }
        }
        #pragma unroll
        for (int j = 0; j < 4; ++j) {
            if (j < cnt) {
                ushort4 o;
                o.x = f2bf(bf2f(av[j].x) * bf2f(bv[j].x));
                o.y = f2bf(bf2f(av[j].y) * bf2f(bv[j].y));
                o.z = f2bf(bf2f(av[j].z) * bf2f(bv[j].z));
                o.w = f2bf(bf2f(av[j].w) * bf2f(bv[j].w));
                em4[e + j * nthr] = o;
            }
        }
    }
    __syncthreads();
    for (int s = tid; s < S; s += nthr) {
        const uint4* base = (const uint4*)(sp + (size_t)s * CC);
        uint4 q[8];
        #pragma unroll
        for (int j = 0; j < 8; ++j) q[j] = base[j];
        unsigned int uu[32];
        #pragma unroll
        for (int j = 0; j < 8; ++j) {
            uu[j * 4 + 0] = q[j].x; uu[j * 4 + 1] = q[j].y;
            uu[j * 4 + 2] = q[j].z; uu[j * 4 + 3] = q[j].w;
        }
        ushort4 t[32];
        #pragma unroll
        for (int c = 0; c < 32; ++c) t[c] = *(const ushort4*)(emB + (uu[c] & 0xFFFFu));
        float4 su = {0.f, 0.f, 0.f, 0.f};
        #pragma unroll
        for (int c = 0; c < 32; ++c) {
            float w = bf2f((unsigned short)(uu[c] >> 16));
            su.x = fmaf(bf2f(t[c].x), w, su.x);
            su.y = fmaf(bf2f(t[c].y), w, su.y);
            su.z = fmaf(bf2f(t[c].z), w, su.z);
            su.w = fmaf(bf2f(t[c].w), w, su.w);
        }
        ushort4 o;
        o.x = f2bf(su.x); o.y = f2bf(su.y);
        o.z = f2bf(su.z); o.w = f2bf(su.w);
        nm4[s] = o;
    }
    __syncthreads();
}

template <typename NMP>
static __device__ __forceinline__ void do_root(NMP nm4, const ushort4* __restrict__ rpk,
                                               float* __restrict__ out, int b0, int tid) {
    const char* nmB = (const char*)&nm4[0];
    if (tid < 4) {
        int col = tid;
        float su = 0.f;
        #pragma unroll
        for (int c = 0; c < CC; ++c) {
            ushort4 r = rpk[c];
            ushort4 a = *(const ushort4*)(nmB + r.x);
            ushort4 b = *(const ushort4*)(nmB + r.y);
            const unsigned short* ap = &a.x;
            const unsigned short* bp = &b.x;
            su = fmaf(bf2f(ap[col]) * bf2f(bp[col]), bf2f(r.z), su);
        }
        out[b0 + col] = (flog2(su) - ROOT_LOG2_SCALE) * LN2;
    }
}

// ---------------------------------------------------------------------------
// mega A: block owns 4 batch cols; nm AND em slices in LDS (135 KB, dynamic
// opt-in). 1024 threads. Whole net, __syncthreads-only between phases.
// ---------------------------------------------------------------------------
__global__ void __launch_bounds__(1024, 1) k_mega_lds(
        const int* __restrict__ x, const unsigned short* __restrict__ lpT,
        const unsigned int* __restrict__ ppk, const unsigned int* __restrict__ spk,
        const ushort4* __restrict__ rpk, float* __restrict__ out) {
    extern __shared__ ushort4 smem4[];
    ushort4* nm4 = smem4;                 // [8192] = 64 KB
    ushort4* em4 = smem4 + 8192;          // [8192] = 64 KB
    int* xv = (int*)(smem4 + 16384);      // [4][256] = 4 KB
    int tid = threadIdx.x;
    int b0 = blockIdx.x * 4;

    {
        int c = tid >> 8, v = tid & 255;
        xv[tid] = x[(b0 + c) * VV + v];
    }
    __syncthreads();
    for (int i = tid; i < N0; i += 1024) {   // input gather via transposed lpT
        int v = i >> 5;
        ushort4 o;
        o.x = lpT[(size_t)xv[v]       * N0 + i];
        o.y = lpT[(size_t)xv[256 + v] * N0 + i];
        o.z = lpT[(size_t)xv[512 + v] * N0 + i];
        o.w = lpT[(size_t)xv[768 + v] * N0 + i];
        nm4[i] = o;
    }
    __syncthreads();
    do_layer(nm4, em4, ppk,         spk,          8192, 4096, tid, 1024);
    do_layer(nm4, em4, ppk + 8192,  spk + 131072, 4096, 2048, tid, 1024);
    do_layer(nm4, em4, ppk + 12288, spk + 196608, 2048, 1024, tid, 1024);
    do_root(nm4, rpk, out, b0, tid);
}

// ---------------------------------------------------------------------------
// mega B (fallback if >64KB LDS opt-in fails): em in LDS (64 KB), nm in a
// per-block global slice.
// ---------------------------------------------------------------------------
__global__ void __launch_bounds__(1024, 1) k_mega_glb(
        const int* __restrict__ x, const unsigned short* __restrict__ lpT,
        const unsigned int* __restrict__ ppk, const unsigned int* __restrict__ spk,
        const ushort4* __restrict__ rpk, ushort4* __restrict__ nmg,
        float* __restrict__ out) {
    extern __shared__ ushort4 smem4[];
    ushort4* em4 = smem4;                              // [8192] = 64 KB
    ushort4* nm4 = nmg + (size_t)blockIdx.x * 8192;    // global slice
    int tid = threadIdx.x;
    int b0 = blockIdx.x * 4;

    for (int i = tid; i < N0; i += 1024) {
        int v = i >> 5;
        int x0 = x[(b0 + 0) * VV + v], x1 = x[(b0 + 1) * VV + v];
        int x2 = x[(b0 + 2) * VV + v], x3 = x[(b0 + 3) * VV + v];
        ushort4 o;
        o.x = lpT[(size_t)x0 * N0 + i];
        o.y = lpT[(size_t)x1 * N0 + i];
        o.z = lpT[(size_t)x2 * N0 + i];
        o.w = lpT[(size_t)x3 * N0 + i];
        nm4[i] = o;
    }
    __syncthreads();
    do_layer(nm4, em4, ppk,         spk,          8192, 4096, tid, 1024);
    do_layer(nm4, em4, ppk + 8192,  spk + 131072, 4096, 2048, tid, 1024);
    do_layer(nm4, em4, ppk + 12288, spk + 196608, 2048, 1024, tid, 1024);
    do_root(nm4, rpk, out, b0, tid);
}

// ---------------------------------------------------------------------------
// Launch: 2 dispatches (prep + mega). Deterministic A/B pick by whether the
// 135 KB dynamic-LDS opt-in succeeds.
// ---------------------------------------------------------------------------
extern "C" void kernel_launch(void* const* d_in, const int* in_sizes, int n_in,
                              void* d_out, int out_size, void* d_ws, size_t ws_size,
                              hipStream_t stream) {
    const int*   x         = (const int*)  d_in[0];
    const float* in_logits = (const float*)d_in[1];
    const float* w1        = (const float*)d_in[2];
    const float* w2        = (const float*)d_in[3];
    const float* w3        = (const float*)d_in[4];
    const float* w4        = (const float*)d_in[5];
    const int*   pids1     = (const int*)  d_in[6];
    const int*   pids2     = (const int*)  d_in[7];
    const int*   pids3     = (const int*)  d_in[8];
    const int*   pids4     = (const int*)  d_in[9];
    const int*   cids1     = (const int*)  d_in[10];
    const int*   cids2     = (const int*)  d_in[11];
    const int*   cids3     = (const int*)  d_in[12];
    const int*   cids4     = (const int*)  d_in[13];
    float* out = (float*)d_out;

    char* ws = (char*)d_ws;
    unsigned short* lpT = (unsigned short*)ws;                    // 64*8192 bf16 = 1 MB
    unsigned int*   ppk = (unsigned int*)(ws + 1048576);          // 14336 u32
    unsigned int*   spk = (unsigned int*)(ws + 1105920);          // 229376 u32
    ushort4*        rpk = (ushort4*)(ws + 2023424);               // 32 x 8 B
    ushort4*        nmg = (ushort4*)(ws + 2023936);               // 256*8192*8 B = 16 MB (B only)

    k_prep<<<3001, 256, 0, stream>>>(in_logits, w1, w2, w3, w4,
                                     cids1, cids2, cids3, cids4,
                                     pids1, pids2, pids3, pids4,
                                     lpT, ppk, spk, rpk);

    const int SMEM_A = 135168;  // 64K nm + 64K em + 4K xv
    const int SMEM_B = 65536;   // 64K em
    hipError_t e = hipFuncSetAttribute((const void*)k_mega_lds,
                                       hipFuncAttributeMaxDynamicSharedMemorySize, SMEM_A);
    if (e == hipSuccess) {
        k_mega_lds<<<256, 1024, SMEM_A, stream>>>(x, lpT, ppk, spk, rpk, out);
    } else {
        (void)hipGetLastError();  // clear sticky error from failed opt-in
        hipFuncSetAttribute((const void*)k_mega_glb,
                            hipFuncAttributeMaxDynamicSharedMemorySize, SMEM_B);
        k_mega_glb<<<256, 1024, SMEM_B, stream>>>(x, lpT, ppk, spk, rpk, nmg, out);
    }
}